// Round 21
// baseline (173.587 us; speedup 1.0000x reference)
//
#include <hip/hip_runtime.h>
#include <hip/hip_fp16.h>

#define N_NODES 50000
#define N_EDGES 1600000
#define F 64
#define G_GRAPHS 64
#define C_CLS 5
#define SLOPE 0.2f

#define NBUCKET ((N_NODES + 127) >> 7)   // 391 buckets of 128 nodes
#define ACHUNK 4096
#define NCHUNKS ((N_EDGES + ACHUNK - 1) / ACHUNK)   // 391
#define GTILES ((N_NODES + 63) / 64)                 // 782 gemm tiles
#define CAP 8192                          // max edges per bucket (mean 4092, std 64)
#define XPAD 68                           // X tile row stride: 16B-aligned, bank-spread

__device__ __forceinline__ float lrelu(float x) { return fmaxf(x, SLOPE * x); }

// ---------------- gemm body (shared by the union kernel and gemm2) ----------
// Hh = fp16(X @ W); S/D = f32 attention dots. tile0 = first row of the tile.

__device__ __forceinline__ void gemm_body(
    int tile0, int tid,
    const float* __restrict__ X, const float* __restrict__ W,
    const float* __restrict__ a_s, const float* __restrict__ a_d,
    __half* __restrict__ Hh, float* __restrict__ S, float* __restrict__ D) {
    __shared__ float Wl[F][F];          // 16 KB
    __shared__ float Xl[64][XPAD];      // 17 KB
    __shared__ float as_l[F], ad_l[F];
    for (int i = tid; i < F * F; i += 256) Wl[i >> 6][i & 63] = W[i];
    if (tid < F) { as_l[tid] = a_s[tid]; ad_l[tid] = a_d[tid]; }
    #pragma unroll
    for (int j = 0; j < 4; j++) {
        int q = tid + (j << 8);
        int row = q >> 4;
        int col = (q & 15) << 2;
        int gr = tile0 + row;
        float4 xv = make_float4(0.f, 0.f, 0.f, 0.f);
        if (gr < N_NODES) xv = *(const float4*)&X[gr * F + col];
        Xl[row][col + 0] = xv.x; Xl[row][col + 1] = xv.y;
        Xl[row][col + 2] = xv.z; Xl[row][col + 3] = xv.w;
    }
    __syncthreads();
    int rsub = tid >> 4;          // 0..15
    int cg = (tid & 15) << 2;     // col base
    float acc[4][4];
    #pragma unroll
    for (int i = 0; i < 4; i++)
        #pragma unroll
        for (int c = 0; c < 4; c++) acc[i][c] = 0.f;
    for (int k4 = 0; k4 < F; k4 += 4) {
        float4 w0 = *(const float4*)&Wl[k4 + 0][cg];
        float4 w1 = *(const float4*)&Wl[k4 + 1][cg];
        float4 w2 = *(const float4*)&Wl[k4 + 2][cg];
        float4 w3 = *(const float4*)&Wl[k4 + 3][cg];
        #pragma unroll
        for (int i = 0; i < 4; i++) {
            float4 xv = *(const float4*)&Xl[rsub + (i << 4)][k4];
            acc[i][0] = fmaf(xv.x, w0.x, acc[i][0]); acc[i][1] = fmaf(xv.x, w0.y, acc[i][1]);
            acc[i][2] = fmaf(xv.x, w0.z, acc[i][2]); acc[i][3] = fmaf(xv.x, w0.w, acc[i][3]);
            acc[i][0] = fmaf(xv.y, w1.x, acc[i][0]); acc[i][1] = fmaf(xv.y, w1.y, acc[i][1]);
            acc[i][2] = fmaf(xv.y, w1.z, acc[i][2]); acc[i][3] = fmaf(xv.y, w1.w, acc[i][3]);
            acc[i][0] = fmaf(xv.z, w2.x, acc[i][0]); acc[i][1] = fmaf(xv.z, w2.y, acc[i][1]);
            acc[i][2] = fmaf(xv.z, w2.z, acc[i][2]); acc[i][3] = fmaf(xv.z, w2.w, acc[i][3]);
            acc[i][0] = fmaf(xv.w, w3.x, acc[i][0]); acc[i][1] = fmaf(xv.w, w3.y, acc[i][1]);
            acc[i][2] = fmaf(xv.w, w3.z, acc[i][2]); acc[i][3] = fmaf(xv.w, w3.w, acc[i][3]);
        }
    }
    float as0 = as_l[cg], as1 = as_l[cg + 1], as2 = as_l[cg + 2], as3 = as_l[cg + 3];
    float ad0 = ad_l[cg], ad1 = ad_l[cg + 1], ad2 = ad_l[cg + 2], ad3 = ad_l[cg + 3];
    #pragma unroll
    for (int i = 0; i < 4; i++) {
        int row = tile0 + rsub + (i << 4);
        if (row >= N_NODES) continue;
        __half2 p0 = __floats2half2_rn(acc[i][0], acc[i][1]);
        __half2 p1 = __floats2half2_rn(acc[i][2], acc[i][3]);
        __half2* hp = (__half2*)&Hh[row * F + cg];
        hp[0] = p0; hp[1] = p1;
        float sp = acc[i][0] * as0 + acc[i][1] * as1 + acc[i][2] * as2 + acc[i][3] * as3;
        float dp = acc[i][0] * ad0 + acc[i][1] * ad1 + acc[i][2] * ad2 + acc[i][3] * ad3;
        #pragma unroll
        for (int o = 1; o < 16; o <<= 1) {
            sp += __shfl_xor(sp, o, 64);
            dp += __shfl_xor(dp, o, 64);
        }
        if ((tid & 15) == 0) { S[row] = sp; D[row] = dp; }
    }
}

// ---------------- union dispatch: chunk histograms ++ gemm1 ----------------

__global__ __launch_bounds__(256) void count_gemm1(
    const int* __restrict__ dst, int* __restrict__ Cmat,
    const float* __restrict__ X, const float* __restrict__ W,
    const float* __restrict__ a_s, const float* __restrict__ a_d,
    __half* __restrict__ Hh, float* __restrict__ S, float* __restrict__ D) {
    int tid = threadIdx.x;
    if (blockIdx.x < NCHUNKS) {
        __shared__ int hist[NBUCKET];
        int c = blockIdx.x;
        for (int i = tid; i < NBUCKET; i += 256) hist[i] = 0;
        __syncthreads();
        int base = c * ACHUNK;
        int lim = min(ACHUNK, N_EDGES - base);
        for (int t = tid; t < lim; t += 256) atomicAdd(&hist[dst[base + t] >> 7], 1);
        __syncthreads();
        for (int i = tid; i < NBUCKET; i += 256)
            Cmat[i * NCHUNKS + c] = hist[i];      // transposed: [bucket][chunk]
    } else {
        gemm_body((blockIdx.x - NCHUNKS) * 64, tid, X, W, a_s, a_d, Hh, S, D);
    }
}

// gemm2 standalone (depends on agg1 output). gmax0: block 0 zeroes pool buffer.
__global__ __launch_bounds__(256) void gemm_sd_kernel(
    const float* __restrict__ X, const float* __restrict__ W,
    const float* __restrict__ a_s, const float* __restrict__ a_d,
    __half* __restrict__ Hh, float* __restrict__ S, float* __restrict__ D,
    float* __restrict__ gmax0) {
    int tid = threadIdx.x;
    if (blockIdx.x == 0) {
        for (int i = tid; i < G_GRAPHS * F; i += 256) gmax0[i] = 0.f;
    }
    gemm_body(blockIdx.x * 64, tid, X, W, a_s, a_d, Hh, S, D);
}

// ---------------- CSR build (rest) ----------------

__global__ __launch_bounds__(512) void scan_chunk_offsets(const int* __restrict__ Cmat,
                                                          int* __restrict__ Coff,
                                                          int* __restrict__ gcount) {
    __shared__ int sc[512];
    int tid = threadIdx.x;
    int b = blockIdx.x;
    int v = (tid < NCHUNKS) ? Cmat[b * NCHUNKS + tid] : 0;   // coalesced row read
    sc[tid] = v;
    __syncthreads();
    for (int s = 1; s < 512; s <<= 1) {
        int t = (tid >= s) ? sc[tid - s] : 0;
        __syncthreads();
        sc[tid] += t;
        __syncthreads();
    }
    if (tid < NCHUNKS) Coff[tid * NBUCKET + b] = sc[tid] - v;  // [chunk][bucket]
    if (tid == 0) gcount[b] = sc[511];
}

__global__ __launch_bounds__(512) void bucket_scatter(
    const int* __restrict__ src, const int* __restrict__ dst,
    const int* __restrict__ Cmat, const int* __restrict__ Coff,
    const int* __restrict__ gcount, unsigned int* __restrict__ bedges) {
    __shared__ int cur[NBUCKET];
    __shared__ int dloc[NBUCKET];
    __shared__ int sc[512];
    __shared__ unsigned long long stage[ACHUNK];
    int tid = threadIdx.x;
    int c = blockIdx.x;
    int base = c * ACHUNK;
    int lim = min(ACHUNK, N_EDGES - base);
    int gb = (tid < NBUCKET) ? gcount[tid] : 0;
    sc[tid] = gb;
    __syncthreads();
    for (int s = 1; s < 512; s <<= 1) {
        int t = (tid >= s) ? sc[tid - s] : 0;
        __syncthreads();
        sc[tid] += t;
        __syncthreads();
    }
    int bbase = sc[tid] - gb;
    __syncthreads();
    int v = (tid < NBUCKET) ? Cmat[tid * NCHUNKS + c] : 0;
    sc[tid] = v;
    __syncthreads();
    for (int s = 1; s < 512; s <<= 1) {
        int t = (tid >= s) ? sc[tid - s] : 0;
        __syncthreads();
        sc[tid] += t;
        __syncthreads();
    }
    if (tid < NBUCKET) {
        int loff = sc[tid] - v;
        cur[tid] = loff;
        dloc[tid] = bbase + Coff[c * NBUCKET + tid] - loff;  // coalesced row read
    }
    __syncthreads();
    for (int t = tid; t < lim; t += 512) {
        int d = dst[base + t];
        int pos = atomicAdd(&cur[d >> 7], 1);
        stage[pos] = ((unsigned long long)(unsigned)d << 32) | (unsigned)src[base + t];
    }
    __syncthreads();
    for (int t = tid; t < lim; t += 512) {
        unsigned long long p = stage[t];
        int d = (int)(p >> 32);
        bedges[dloc[d >> 7] + t] =
            ((unsigned)(d & 127) << 17) | (unsigned)(p & 0x1ffffull);
    }
}

__global__ __launch_bounds__(512) void bucket_csr(
    const unsigned int* __restrict__ bedges, const int* __restrict__ gcount,
    int* __restrict__ row_ptr, int* __restrict__ csr_src) {
    __shared__ int hist[128];
    __shared__ int sc[128];
    __shared__ int loff[129];
    __shared__ int cur[128];
    __shared__ int scg[512];
    __shared__ int outs[CAP];
    int tid = threadIdx.x;
    int b = blockIdx.x;
    int nbase = b << 7;
    int nlocal = min(128, N_NODES - nbase);
    int gb = (tid < NBUCKET) ? gcount[tid] : 0;
    scg[tid] = gb;
    __syncthreads();
    for (int s = 1; s < 512; s <<= 1) {
        int t = (tid >= s) ? scg[tid - s] : 0;
        __syncthreads();
        scg[tid] += t;
        __syncthreads();
    }
    int cnt = min(gcount[b], CAP);
    int cbase = scg[b] - gcount[b];
    if (tid < 128) { hist[tid] = 0; cur[tid] = 0; }
    __syncthreads();
    for (int t = tid; t < cnt; t += 512)
        atomicAdd(&hist[(int)(bedges[cbase + t] >> 17)], 1);
    __syncthreads();
    if (tid < 128) sc[tid] = hist[tid];
    __syncthreads();
    for (int s = 1; s < 128; s <<= 1) {
        int t = (tid < 128 && tid >= s) ? sc[tid - s] : 0;
        __syncthreads();
        if (tid < 128) sc[tid] += t;
        __syncthreads();
    }
    if (tid < 128) loff[tid + 1] = sc[tid];
    if (tid == 0) loff[0] = 0;
    __syncthreads();
    for (int t = tid; t < cnt; t += 512) {
        unsigned int p = bedges[cbase + t];
        int dl = (int)(p >> 17);
        int r = atomicAdd(&cur[dl], 1);
        outs[loff[dl] + r] = (int)(p & 0x1ffffu);
    }
    __syncthreads();
    for (int t = tid; t < cnt; t += 512) csr_src[cbase + t] = outs[t];
    for (int i = tid; i < nlocal; i += 512) row_ptr[nbase + i] = cbase + loff[i];
    if (b == NBUCKET - 1 && tid == 0) row_ptr[N_NODES] = cbase + loff[nlocal];
}

// ---------------- per-node softmax aggregation (shfl-free gather) ----------
// wave = node; 8 edge-slots x 8 lanes, fp16x8 (16B float4) per lane.
// Gather addresses come from DIRECT csr_src loads (linear, L2-hot, 8-lane
// broadcast) + recomputed p, instead of 2 DS-pipe shfls per iteration ->
// no cross-lane dependency on the load path; unified any-degree loop.

struct F8 { float v0, v1, v2, v3, v4, v5, v6, v7; };
__device__ __forceinline__ F8 h8_unpack(float4 r) {
    F8 f;
    __half2 a01 = *reinterpret_cast<__half2*>(&r.x);
    __half2 a23 = *reinterpret_cast<__half2*>(&r.y);
    __half2 a45 = *reinterpret_cast<__half2*>(&r.z);
    __half2 a67 = *reinterpret_cast<__half2*>(&r.w);
    f.v0 = __low2float(a01); f.v1 = __high2float(a01);
    f.v2 = __low2float(a23); f.v3 = __high2float(a23);
    f.v4 = __low2float(a45); f.v5 = __high2float(a45);
    f.v6 = __low2float(a67); f.v7 = __high2float(a67);
    return f;
}

#define ACC8(P, G) do { \
    a0 = fmaf(P, (G).v0, a0); a1 = fmaf(P, (G).v1, a1); \
    a2 = fmaf(P, (G).v2, a2); a3 = fmaf(P, (G).v3, a3); \
    a4 = fmaf(P, (G).v4, a4); a5 = fmaf(P, (G).v5, a5); \
    a6 = fmaf(P, (G).v6, a6); a7 = fmaf(P, (G).v7, a7); } while (0)

// Shared body: computes this node's output into o0/o1 (valid in lanes g==0).
#define AGG_BODY() \
    int lane = threadIdx.x & 63; \
    int i = (blockIdx.x * blockDim.x + threadIdx.x) >> 6; \
    if (i >= N_NODES) return; \
    int start = row_ptr[i], end = row_ptr[i + 1]; \
    int deg = end - start; \
    float d_i = Dv[i]; \
    float eself = lrelu(S[i] + d_i); \
    int g  = lane >> 3; \
    int fl = (lane & 7) << 3; \
    float a0 = 0.f, a1 = 0.f, a2 = 0.f, a3 = 0.f; \
    float a4 = 0.f, a5 = 0.f, a6 = 0.f, a7 = 0.f; \
    /* pass 1: max over edges (edge per lane, coalesced) */ \
    float m = eself; \
    for (int j = start + lane; j < end; j += 64) \
        m = fmaxf(m, lrelu(S[csr_src[j]] + d_i)); \
    _Pragma("unroll") \
    for (int o = 32; o > 0; o >>= 1) m = fmaxf(m, __shfl_xor(m, o, 64)); \
    /* pass 2: z (recompute, L2-hot) */ \
    float zlane = 0.f; \
    for (int j = start + lane; j < end; j += 64) \
        zlane += __expf(lrelu(S[csr_src[j]] + d_i) - m); \
    _Pragma("unroll") \
    for (int o = 32; o > 0; o >>= 1) zlane += __shfl_xor(zlane, o, 64); \
    float pself = __expf(eself - m); \
    float z = zlane + pself; \
    F8 hs = h8_unpack(*(const float4*)&Hh[i * F + fl]); \
    if (g == 0) { \
        a0 = pself * hs.v0; a1 = pself * hs.v1; a2 = pself * hs.v2; a3 = pself * hs.v3; \
        a4 = pself * hs.v4; a5 = pself * hs.v5; a6 = pself * hs.v6; a7 = pself * hs.v7; \
    } \
    /* main: slot t*8+g per lane; direct loads, depth-2 pipeline */ \
    int iters = (deg + 7) >> 3; \
    if (iters > 0) { \
        int slot = g; \
        bool vv = slot < deg; \
        int sj0 = vv ? csr_src[start + slot] : 0; \
        float e0 = vv ? lrelu(S[sj0] + d_i) : -1e30f; \
        float4 v0 = *(const float4*)&Hh[sj0 * F + fl]; \
        for (int t = 1; t < iters; t++) { \
            int slot1 = (t << 3) + g; \
            bool v1v = slot1 < deg; \
            int sj1 = v1v ? csr_src[start + slot1] : 0; \
            float e1 = v1v ? lrelu(S[sj1] + d_i) : -1e30f; \
            float4 v1 = *(const float4*)&Hh[sj1 * F + fl]; \
            float p0 = __expf(e0 - m); \
            F8 gg = h8_unpack(v0); \
            ACC8(p0, gg); \
            e0 = e1; v0 = v1; \
        } \
        float p0 = __expf(e0 - m); \
        F8 gg = h8_unpack(v0); \
        ACC8(p0, gg); \
    } \
    _Pragma("unroll") \
    for (int o = 8; o <= 32; o <<= 1) { \
        a0 += __shfl_xor(a0, o, 64); a1 += __shfl_xor(a1, o, 64); \
        a2 += __shfl_xor(a2, o, 64); a3 += __shfl_xor(a3, o, 64); \
        a4 += __shfl_xor(a4, o, 64); a5 += __shfl_xor(a5, o, 64); \
        a6 += __shfl_xor(a6, o, 64); a7 += __shfl_xor(a7, o, 64); \
    } \
    float4 o0, o1; \
    if (g == 0) { \
        float rz = 1.0f / z; \
        float4 b0 = *(const float4*)&bias[fl]; \
        float4 b1 = *(const float4*)&bias[fl + 4]; \
        o0.x = fmaxf(a0 * rz + b0.x, 0.f); \
        o0.y = fmaxf(a1 * rz + b0.y, 0.f); \
        o0.z = fmaxf(a2 * rz + b0.z, 0.f); \
        o0.w = fmaxf(a3 * rz + b0.w, 0.f); \
        o1.x = fmaxf(a4 * rz + b1.x, 0.f); \
        o1.y = fmaxf(a5 * rz + b1.y, 0.f); \
        o1.z = fmaxf(a6 * rz + b1.z, 0.f); \
        o1.w = fmaxf(a7 * rz + b1.w, 0.f); \
    }

// layer-1 variant: plain output write, no pool code anywhere
__global__ __launch_bounds__(256) void agg_main(
    const __half* __restrict__ Hh, const float* __restrict__ S, const float* __restrict__ Dv,
    const int* __restrict__ row_ptr, const int* __restrict__ csr_src,
    const float* __restrict__ bias, float* __restrict__ OUT) {
    AGG_BODY()
    if (g == 0) {
        *(float4*)&OUT[i * F + fl] = o0;       // both layers have ReLU after
        *(float4*)&OUT[i * F + fl + 4] = o1;
    }
}

// layer-2 variant: pool fused via LDS run-reduce over the block's 4 nodes,
// then ~1 atomicMax per feature per block (R19: per-wave atomics serialize
// ~780-deep per address -> 435us; pre-reduction is essential).
__global__ __launch_bounds__(256) void agg_pool(
    const __half* __restrict__ Hh, const float* __restrict__ S, const float* __restrict__ Dv,
    const int* __restrict__ row_ptr, const int* __restrict__ csr_src,
    const float* __restrict__ bias,
    const int* __restrict__ batch, float* __restrict__ gmax) {
    __shared__ float pout[4][F];
    __shared__ int   pbat[4];
    AGG_BODY()
    int wid = threadIdx.x >> 6;
    if (g == 0) {
        *(float4*)&pout[wid][fl] = o0;
        *(float4*)&pout[wid][fl + 4] = o1;
        if (lane == 0) pbat[wid] = batch[i];
    }
    __syncthreads();
    if (threadIdx.x < F) {
        int f = threadIdx.x;
        int curb = pbat[0];
        float mx = pout[0][f];
        #pragma unroll
        for (int r = 1; r < 4; r++) {
            int b = pbat[r];
            float v = pout[r][f];
            if (b != curb) {
                atomicMax((int*)&gmax[curb * F + f], __float_as_int(mx));
                curb = b; mx = v;
            } else {
                mx = fmaxf(mx, v);
            }
        }
        atomicMax((int*)&gmax[curb * F + f], __float_as_int(mx));
    }
}

// ---------------- final linear ----------------

__global__ void final_kernel(const float* __restrict__ gmax, const float* __restrict__ Wl,
                             const float* __restrict__ bl, float* __restrict__ out) {
    int g = blockIdx.x;
    int c = threadIdx.x;
    if (c < C_CLS) {
        float acc = bl[c];
        #pragma unroll
        for (int f = 0; f < F; f++) acc = fmaf(gmax[g * F + f], Wl[f * C_CLS + c], acc);
        out[g * C_CLS + c] = acc;
    }
}

// ---------------- launch ----------------

extern "C" void kernel_launch(void* const* d_in, const int* in_sizes, int n_in,
                              void* d_out, int out_size, void* d_ws, size_t ws_size,
                              hipStream_t stream) {
    const float* x    = (const float*)d_in[0];
    const int*   ei   = (const int*)d_in[1];
    const int*   batch= (const int*)d_in[2];
    const float* W1   = (const float*)d_in[3];
    const float* a1s  = (const float*)d_in[4];
    const float* a1d  = (const float*)d_in[5];
    const float* b1   = (const float*)d_in[6];
    const float* W2   = (const float*)d_in[7];
    const float* a2s  = (const float*)d_in[8];
    const float* a2d  = (const float*)d_in[9];
    const float* b2   = (const float*)d_in[10];
    const float* Wl   = (const float*)d_in[11];
    const float* bl   = (const float*)d_in[12];
    float* out = (float*)d_out;

    const int* src = ei;
    const int* dst = ei + N_EDGES;

    // workspace layout (256B aligned); ws is large enough for all buffers separate
    char* ws = (char*)d_ws;
    size_t off = 0;
    auto alloc = [&](size_t bytes) { size_t o = off; off += (bytes + 255) & ~(size_t)255; return o; };
    int*   row_ptr = (int*)(ws + alloc((size_t)(N_NODES + 1) * 4));
    int*   csr_src = (int*)(ws + alloc((size_t)N_EDGES * 4));
    unsigned int* bedges = (unsigned int*)(ws + alloc((size_t)N_EDGES * 4));
    __half* Hh     = (__half*)(ws + alloc((size_t)N_NODES * F * 2));
    float* hB      = (float*)(ws + alloc((size_t)N_NODES * F * 4));
    int*   Cmat    = (int*)(ws + alloc((size_t)NBUCKET * NCHUNKS * 4));
    int*   Coff    = (int*)(ws + alloc((size_t)NCHUNKS * NBUCKET * 4));
    float* Sv      = (float*)(ws + alloc((size_t)N_NODES * 4));
    float* Dv      = (float*)(ws + alloc((size_t)N_NODES * 4));
    float* gmax    = (float*)(ws + alloc((size_t)G_GRAPHS * F * 4));
    int*   gcount  = (int*)(ws + alloc((size_t)NBUCKET * 4));

    // ---- dispatch 1: chunk histograms ++ gemm1 (independent work, unioned) ----
    count_gemm1<<<NCHUNKS + GTILES, 256, 0, stream>>>(dst, Cmat, x, W1, a1s, a1d, Hh, Sv, Dv);
    // ---- CSR build (deterministic bucketed counting sort, u32 records) ----
    scan_chunk_offsets<<<NBUCKET, 512, 0, stream>>>(Cmat, Coff, gcount);
    bucket_scatter<<<NCHUNKS, 512, 0, stream>>>(src, dst, Cmat, Coff, gcount, bedges);
    bucket_csr<<<NBUCKET, 512, 0, stream>>>(bedges, gcount, row_ptr, csr_src);

    // ---- layer 1 agg: Hh/Sv/Dv ready since dispatch 1 ----
    agg_main<<<(N_NODES * 64 + 255) / 256, 256, 0, stream>>>(Hh, Sv, Dv, row_ptr, csr_src, b1, hB);

    // ---- layer 2: gemm(hB) -> Hh(fp16) -> agg (pool fused into gmax) ----
    gemm_sd_kernel<<<GTILES, 256, 0, stream>>>(hB, W2, a2s, a2d, Hh, Sv, Dv, gmax);
    agg_pool<<<(N_NODES * 64 + 255) / 256, 256, 0, stream>>>(Hh, Sv, Dv, row_ptr, csr_src, b2,
                                                             batch, gmax);

    // ---- classifier ----
    final_kernel<<<G_GRAPHS, 64, 0, stream>>>(gmax, Wl, bl, out);
}

// Round 22
// 149.387 us; speedup vs baseline: 1.1620x; 1.1620x over previous
//
#include <hip/hip_runtime.h>
#include <hip/hip_fp16.h>

#define N_NODES 50000
#define N_EDGES 1600000
#define F 64
#define G_GRAPHS 64
#define C_CLS 5
#define SLOPE 0.2f

#define NBUCKET ((N_NODES + 127) >> 7)   // 391 buckets of 128 nodes
#define ACHUNK 4096
#define NCHUNKS ((N_EDGES + ACHUNK - 1) / ACHUNK)   // 391
#define GTILES ((N_NODES + 63) / 64)                 // 782 gemm tiles
#define CAP 8192                          // max edges per bucket (mean 4092, std 64)
#define MAXCH 4                           // reg-cached chunks: degree <= 256 fast path
#define XPAD 68                           // X tile row stride: 16B-aligned, bank-spread

__device__ __forceinline__ float lrelu(float x) { return fmaxf(x, SLOPE * x); }

// ---------------- gemm body (shared by the union kernel and gemm2) ----------
// Hh = fp16(X @ W); S/D = f32 attention dots. tile0 = first row of the tile.

__device__ __forceinline__ void gemm_body(
    int tile0, int tid,
    const float* __restrict__ X, const float* __restrict__ W,
    const float* __restrict__ a_s, const float* __restrict__ a_d,
    __half* __restrict__ Hh, float* __restrict__ S, float* __restrict__ D) {
    __shared__ float Wl[F][F];          // 16 KB
    __shared__ float Xl[64][XPAD];      // 17 KB
    __shared__ float as_l[F], ad_l[F];
    for (int i = tid; i < F * F; i += 256) Wl[i >> 6][i & 63] = W[i];
    if (tid < F) { as_l[tid] = a_s[tid]; ad_l[tid] = a_d[tid]; }
    #pragma unroll
    for (int j = 0; j < 4; j++) {
        int q = tid + (j << 8);
        int row = q >> 4;
        int col = (q & 15) << 2;
        int gr = tile0 + row;
        float4 xv = make_float4(0.f, 0.f, 0.f, 0.f);
        if (gr < N_NODES) xv = *(const float4*)&X[gr * F + col];
        Xl[row][col + 0] = xv.x; Xl[row][col + 1] = xv.y;
        Xl[row][col + 2] = xv.z; Xl[row][col + 3] = xv.w;
    }
    __syncthreads();
    int rsub = tid >> 4;          // 0..15
    int cg = (tid & 15) << 2;     // col base
    float acc[4][4];
    #pragma unroll
    for (int i = 0; i < 4; i++)
        #pragma unroll
        for (int c = 0; c < 4; c++) acc[i][c] = 0.f;
    for (int k4 = 0; k4 < F; k4 += 4) {
        float4 w0 = *(const float4*)&Wl[k4 + 0][cg];
        float4 w1 = *(const float4*)&Wl[k4 + 1][cg];
        float4 w2 = *(const float4*)&Wl[k4 + 2][cg];
        float4 w3 = *(const float4*)&Wl[k4 + 3][cg];
        #pragma unroll
        for (int i = 0; i < 4; i++) {
            float4 xv = *(const float4*)&Xl[rsub + (i << 4)][k4];
            acc[i][0] = fmaf(xv.x, w0.x, acc[i][0]); acc[i][1] = fmaf(xv.x, w0.y, acc[i][1]);
            acc[i][2] = fmaf(xv.x, w0.z, acc[i][2]); acc[i][3] = fmaf(xv.x, w0.w, acc[i][3]);
            acc[i][0] = fmaf(xv.y, w1.x, acc[i][0]); acc[i][1] = fmaf(xv.y, w1.y, acc[i][1]);
            acc[i][2] = fmaf(xv.y, w1.z, acc[i][2]); acc[i][3] = fmaf(xv.y, w1.w, acc[i][3]);
            acc[i][0] = fmaf(xv.z, w2.x, acc[i][0]); acc[i][1] = fmaf(xv.z, w2.y, acc[i][1]);
            acc[i][2] = fmaf(xv.z, w2.z, acc[i][2]); acc[i][3] = fmaf(xv.z, w2.w, acc[i][3]);
            acc[i][0] = fmaf(xv.w, w3.x, acc[i][0]); acc[i][1] = fmaf(xv.w, w3.y, acc[i][1]);
            acc[i][2] = fmaf(xv.w, w3.z, acc[i][2]); acc[i][3] = fmaf(xv.w, w3.w, acc[i][3]);
        }
    }
    float as0 = as_l[cg], as1 = as_l[cg + 1], as2 = as_l[cg + 2], as3 = as_l[cg + 3];
    float ad0 = ad_l[cg], ad1 = ad_l[cg + 1], ad2 = ad_l[cg + 2], ad3 = ad_l[cg + 3];
    #pragma unroll
    for (int i = 0; i < 4; i++) {
        int row = tile0 + rsub + (i << 4);
        if (row >= N_NODES) continue;
        __half2 p0 = __floats2half2_rn(acc[i][0], acc[i][1]);
        __half2 p1 = __floats2half2_rn(acc[i][2], acc[i][3]);
        __half2* hp = (__half2*)&Hh[row * F + cg];
        hp[0] = p0; hp[1] = p1;
        float sp = acc[i][0] * as0 + acc[i][1] * as1 + acc[i][2] * as2 + acc[i][3] * as3;
        float dp = acc[i][0] * ad0 + acc[i][1] * ad1 + acc[i][2] * ad2 + acc[i][3] * ad3;
        #pragma unroll
        for (int o = 1; o < 16; o <<= 1) {
            sp += __shfl_xor(sp, o, 64);
            dp += __shfl_xor(dp, o, 64);
        }
        if ((tid & 15) == 0) { S[row] = sp; D[row] = dp; }
    }
}

// ---------------- union dispatch: chunk histograms ++ gemm1 ----------------
// Blocks [0,NCHUNKS): per-chunk bucket histogram -> Cmat[bucket][chunk]
// Blocks [NCHUNKS, NCHUNKS+GTILES): gemm1 tile (independent of CSR data).

__global__ __launch_bounds__(256) void count_gemm1(
    const int* __restrict__ dst, int* __restrict__ Cmat,
    const float* __restrict__ X, const float* __restrict__ W,
    const float* __restrict__ a_s, const float* __restrict__ a_d,
    __half* __restrict__ Hh, float* __restrict__ S, float* __restrict__ D) {
    int tid = threadIdx.x;
    if (blockIdx.x < NCHUNKS) {
        __shared__ int hist[NBUCKET];
        int c = blockIdx.x;
        for (int i = tid; i < NBUCKET; i += 256) hist[i] = 0;
        __syncthreads();
        int base = c * ACHUNK;
        int lim = min(ACHUNK, N_EDGES - base);
        for (int t = tid; t < lim; t += 256) atomicAdd(&hist[dst[base + t] >> 7], 1);
        __syncthreads();
        for (int i = tid; i < NBUCKET; i += 256)
            Cmat[i * NCHUNKS + c] = hist[i];      // transposed: [bucket][chunk]
    } else {
        gemm_body((blockIdx.x - NCHUNKS) * 64, tid, X, W, a_s, a_d, Hh, S, D);
    }
}

// gemm2 standalone (depends on agg1 output). gmax0: block 0 zeroes pool buffer.
__global__ __launch_bounds__(256) void gemm_sd_kernel(
    const float* __restrict__ X, const float* __restrict__ W,
    const float* __restrict__ a_s, const float* __restrict__ a_d,
    __half* __restrict__ Hh, float* __restrict__ S, float* __restrict__ D,
    float* __restrict__ gmax0) {
    int tid = threadIdx.x;
    if (blockIdx.x == 0) {
        for (int i = tid; i < G_GRAPHS * F; i += 256) gmax0[i] = 0.f;
    }
    gemm_body(blockIdx.x * 64, tid, X, W, a_s, a_d, Hh, S, D);
}

// ---------------- CSR build (rest) ----------------
// Cmat is [bucket][chunk] -> scan_chunk_offsets reads rows COALESCED.
// Coff is [chunk][bucket] -> bucket_scatter reads rows COALESCED.

__global__ __launch_bounds__(512) void scan_chunk_offsets(const int* __restrict__ Cmat,
                                                          int* __restrict__ Coff,
                                                          int* __restrict__ gcount) {
    __shared__ int sc[512];
    int tid = threadIdx.x;
    int b = blockIdx.x;
    int v = (tid < NCHUNKS) ? Cmat[b * NCHUNKS + tid] : 0;   // coalesced row read
    sc[tid] = v;
    __syncthreads();
    for (int s = 1; s < 512; s <<= 1) {
        int t = (tid >= s) ? sc[tid - s] : 0;
        __syncthreads();
        sc[tid] += t;
        __syncthreads();
    }
    if (tid < NCHUNKS) Coff[tid * NBUCKET + b] = sc[tid] - v;  // [chunk][bucket]
    if (tid == 0) gcount[b] = sc[511];
}

// chunk-local LDS counting sort; histogram from Cmat; bucket_base from gcount scan
__global__ __launch_bounds__(512) void bucket_scatter(
    const int* __restrict__ src, const int* __restrict__ dst,
    const int* __restrict__ Cmat, const int* __restrict__ Coff,
    const int* __restrict__ gcount, unsigned int* __restrict__ bedges) {
    __shared__ int cur[NBUCKET];
    __shared__ int dloc[NBUCKET];
    __shared__ int sc[512];
    __shared__ unsigned long long stage[ACHUNK];
    int tid = threadIdx.x;
    int c = blockIdx.x;
    int base = c * ACHUNK;
    int lim = min(ACHUNK, N_EDGES - base);
    // scan 1: gcount -> exclusive bucket_base
    int gb = (tid < NBUCKET) ? gcount[tid] : 0;
    sc[tid] = gb;
    __syncthreads();
    for (int s = 1; s < 512; s <<= 1) {
        int t = (tid >= s) ? sc[tid - s] : 0;
        __syncthreads();
        sc[tid] += t;
        __syncthreads();
    }
    int bbase = sc[tid] - gb;
    __syncthreads();
    // scan 2: this chunk's bucket counts
    int v = (tid < NBUCKET) ? Cmat[tid * NCHUNKS + c] : 0;
    sc[tid] = v;
    __syncthreads();
    for (int s = 1; s < 512; s <<= 1) {
        int t = (tid >= s) ? sc[tid - s] : 0;
        __syncthreads();
        sc[tid] += t;
        __syncthreads();
    }
    if (tid < NBUCKET) {
        int loff = sc[tid] - v;
        cur[tid] = loff;
        dloc[tid] = bbase + Coff[c * NBUCKET + tid] - loff;  // coalesced row read
    }
    __syncthreads();
    for (int t = tid; t < lim; t += 512) {
        int d = dst[base + t];
        int pos = atomicAdd(&cur[d >> 7], 1);
        stage[pos] = ((unsigned long long)(unsigned)d << 32) | (unsigned)src[base + t];
    }
    __syncthreads();
    for (int t = tid; t < lim; t += 512) {
        unsigned long long p = stage[t];
        int d = (int)(p >> 32);
        bedges[dloc[d >> 7] + t] =
            ((unsigned)(d & 127) << 17) | (unsigned)(p & 0x1ffffull);
    }
}

__global__ __launch_bounds__(512) void bucket_csr(
    const unsigned int* __restrict__ bedges, const int* __restrict__ gcount,
    int* __restrict__ row_ptr, int* __restrict__ csr_src) {
    __shared__ int hist[128];
    __shared__ int sc[128];
    __shared__ int loff[129];
    __shared__ int cur[128];
    __shared__ int scg[512];
    __shared__ int outs[CAP];
    int tid = threadIdx.x;
    int b = blockIdx.x;
    int nbase = b << 7;
    int nlocal = min(128, N_NODES - nbase);
    int gb = (tid < NBUCKET) ? gcount[tid] : 0;
    scg[tid] = gb;
    __syncthreads();
    for (int s = 1; s < 512; s <<= 1) {
        int t = (tid >= s) ? scg[tid - s] : 0;
        __syncthreads();
        scg[tid] += t;
        __syncthreads();
    }
    int cnt = min(gcount[b], CAP);
    int cbase = scg[b] - gcount[b];
    if (tid < 128) { hist[tid] = 0; cur[tid] = 0; }
    __syncthreads();
    for (int t = tid; t < cnt; t += 512)
        atomicAdd(&hist[(int)(bedges[cbase + t] >> 17)], 1);
    __syncthreads();
    if (tid < 128) sc[tid] = hist[tid];
    __syncthreads();
    for (int s = 1; s < 128; s <<= 1) {
        int t = (tid < 128 && tid >= s) ? sc[tid - s] : 0;
        __syncthreads();
        if (tid < 128) sc[tid] += t;
        __syncthreads();
    }
    if (tid < 128) loff[tid + 1] = sc[tid];
    if (tid == 0) loff[0] = 0;
    __syncthreads();
    for (int t = tid; t < cnt; t += 512) {
        unsigned int p = bedges[cbase + t];
        int dl = (int)(p >> 17);
        int r = atomicAdd(&cur[dl], 1);
        outs[loff[dl] + r] = (int)(p & 0x1ffffu);
    }
    __syncthreads();
    for (int t = tid; t < cnt; t += 512) csr_src[cbase + t] = outs[t];
    for (int i = tid; i < nlocal; i += 512) row_ptr[nbase + i] = cbase + loff[i];
    if (b == NBUCKET - 1 && tid == 0) row_ptr[N_NODES] = cbase + loff[nlocal];
}

// ---------------- per-node softmax aggregation ----------------
// wave = node; 8 edge-slots x 8 lanes, fp16x8 (16B float4) per lane ->
// 8 source rows per wave-wide load; depth-2 prefetch -> 2 loads in flight.
// (R21: replacing shfl-distributed sj/p with direct csr_src loads regressed
// 49->62us: the address chain became L2-load->gather instead of shfl->gather.)

struct F8 { float v0, v1, v2, v3, v4, v5, v6, v7; };
__device__ __forceinline__ F8 h8_unpack(float4 r) {
    F8 f;
    __half2 a01 = *reinterpret_cast<__half2*>(&r.x);
    __half2 a23 = *reinterpret_cast<__half2*>(&r.y);
    __half2 a45 = *reinterpret_cast<__half2*>(&r.z);
    __half2 a67 = *reinterpret_cast<__half2*>(&r.w);
    f.v0 = __low2float(a01); f.v1 = __high2float(a01);
    f.v2 = __low2float(a23); f.v3 = __high2float(a23);
    f.v4 = __low2float(a45); f.v5 = __high2float(a45);
    f.v6 = __low2float(a67); f.v7 = __high2float(a67);
    return f;
}

#define ACC8(P, G) do { \
    a0 = fmaf(P, (G).v0, a0); a1 = fmaf(P, (G).v1, a1); \
    a2 = fmaf(P, (G).v2, a2); a3 = fmaf(P, (G).v3, a3); \
    a4 = fmaf(P, (G).v4, a4); a5 = fmaf(P, (G).v5, a5); \
    a6 = fmaf(P, (G).v6, a6); a7 = fmaf(P, (G).v7, a7); } while (0)

// Shared body: computes this node's output into o0/o1 (valid in lanes g==0).
#define AGG_BODY() \
    int lane = threadIdx.x & 63; \
    int i = (blockIdx.x * blockDim.x + threadIdx.x) >> 6; \
    if (i >= N_NODES) return; \
    int start = row_ptr[i], end = row_ptr[i + 1]; \
    int deg = end - start; \
    int nch = (deg + 63) >> 6; \
    float d_i = Dv[i]; \
    float eself = lrelu(S[i] + d_i); \
    int g  = lane >> 3; \
    int fl = (lane & 7) << 3; \
    float a0 = 0.f, a1 = 0.f, a2 = 0.f, a3 = 0.f; \
    float a4 = 0.f, a5 = 0.f, a6 = 0.f, a7 = 0.f; \
    float z; \
    if (nch <= MAXCH) { \
        int   sj_reg[MAXCH]; \
        float p_reg[MAXCH]; \
        float m = eself; \
        _Pragma("unroll") \
        for (int c = 0; c < MAXCH; c++) { \
            int j = start + (c << 6) + lane; \
            bool v = (c < nch) && (j < end); \
            int sj = v ? csr_src[j] : 0; \
            float e = v ? lrelu(S[sj] + d_i) : -1e30f; \
            sj_reg[c] = sj; \
            p_reg[c] = e; \
            m = fmaxf(m, e); \
        } \
        _Pragma("unroll") \
        for (int o = 32; o > 0; o >>= 1) m = fmaxf(m, __shfl_xor(m, o, 64)); \
        float zlane = 0.f; \
        _Pragma("unroll") \
        for (int c = 0; c < MAXCH; c++) { \
            if (c < nch) { \
                float p = __expf(p_reg[c] - m); \
                p_reg[c] = p; \
                zlane += p; \
            } \
        } \
        _Pragma("unroll") \
        for (int o = 32; o > 0; o >>= 1) zlane += __shfl_xor(zlane, o, 64); \
        float pself = __expf(eself - m); \
        z = zlane + pself; \
        F8 hs = h8_unpack(*(const float4*)&Hh[i * F + fl]); \
        if (g == 0) { \
            a0 = pself * hs.v0; a1 = pself * hs.v1; a2 = pself * hs.v2; a3 = pself * hs.v3; \
            a4 = pself * hs.v4; a5 = pself * hs.v5; a6 = pself * hs.v6; a7 = pself * hs.v7; \
        } \
        _Pragma("unroll") \
        for (int c = 0; c < MAXCH; c++) { \
            if (c >= nch) break; \
            int cnt = min(64, deg - (c << 6)); \
            int iters = (cnt + 7) >> 3; \
            float pj0 = __shfl(p_reg[c], g, 64); \
            int   sj0 = __shfl(sj_reg[c], g, 64); \
            float4 v0 = *(const float4*)&Hh[sj0 * F + fl]; \
            for (int t = 1; t < iters; t++) { \
                int slot = (t << 3) + g; \
                float pj1 = __shfl(p_reg[c], slot, 64); \
                int   sj1 = __shfl(sj_reg[c], slot, 64); \
                float4 v1 = *(const float4*)&Hh[sj1 * F + fl]; \
                F8 gg = h8_unpack(v0); \
                ACC8(pj0, gg); \
                pj0 = pj1; v0 = v1; \
            } \
            F8 gg = h8_unpack(v0); \
            ACC8(pj0, gg); \
        } \
    } else { \
        float m = eself; \
        for (int j = start + lane; j < end; j += 64) \
            m = fmaxf(m, lrelu(S[csr_src[j]] + d_i)); \
        _Pragma("unroll") \
        for (int o = 32; o > 0; o >>= 1) m = fmaxf(m, __shfl_xor(m, o, 64)); \
        float pself = __expf(eself - m); \
        float zlane = 0.f; \
        F8 hs = h8_unpack(*(const float4*)&Hh[i * F + fl]); \
        if (g == 0) { \
            a0 = pself * hs.v0; a1 = pself * hs.v1; a2 = pself * hs.v2; a3 = pself * hs.v3; \
            a4 = pself * hs.v4; a5 = pself * hs.v5; a6 = pself * hs.v6; a7 = pself * hs.v7; \
        } \
        for (int cb = start; cb < end; cb += 64) { \
            int j = cb + lane; \
            bool v = j < end; \
            int sj = v ? csr_src[j] : 0; \
            float p = v ? __expf(lrelu(S[sj] + d_i) - m) : 0.f; \
            zlane += p; \
            int cnt = min(64, end - cb); \
            int iters = (cnt + 7) >> 3; \
            for (int t = 0; t < iters; t++) { \
                int slot = (t << 3) + g; \
                float pj = __shfl(p, slot, 64); \
                int  sjt = __shfl(sj, slot, 64); \
                F8 gg = h8_unpack(*(const float4*)&Hh[sjt * F + fl]); \
                ACC8(pj, gg); \
            } \
        } \
        _Pragma("unroll") \
        for (int o = 32; o > 0; o >>= 1) zlane += __shfl_xor(zlane, o, 64); \
        z = zlane + pself; \
    } \
    _Pragma("unroll") \
    for (int o = 8; o <= 32; o <<= 1) { \
        a0 += __shfl_xor(a0, o, 64); a1 += __shfl_xor(a1, o, 64); \
        a2 += __shfl_xor(a2, o, 64); a3 += __shfl_xor(a3, o, 64); \
        a4 += __shfl_xor(a4, o, 64); a5 += __shfl_xor(a5, o, 64); \
        a6 += __shfl_xor(a6, o, 64); a7 += __shfl_xor(a7, o, 64); \
    } \
    float4 o0, o1; \
    if (g == 0) { \
        float rz = 1.0f / z; \
        float4 b0 = *(const float4*)&bias[fl]; \
        float4 b1 = *(const float4*)&bias[fl + 4]; \
        o0.x = fmaxf(a0 * rz + b0.x, 0.f); \
        o0.y = fmaxf(a1 * rz + b0.y, 0.f); \
        o0.z = fmaxf(a2 * rz + b0.z, 0.f); \
        o0.w = fmaxf(a3 * rz + b0.w, 0.f); \
        o1.x = fmaxf(a4 * rz + b1.x, 0.f); \
        o1.y = fmaxf(a5 * rz + b1.y, 0.f); \
        o1.z = fmaxf(a6 * rz + b1.z, 0.f); \
        o1.w = fmaxf(a7 * rz + b1.w, 0.f); \
    }

// layer-1 variant: plain output write, no pool code anywhere
__global__ __launch_bounds__(256) void agg_main(
    const __half* __restrict__ Hh, const float* __restrict__ S, const float* __restrict__ Dv,
    const int* __restrict__ row_ptr, const int* __restrict__ csr_src,
    const float* __restrict__ bias, float* __restrict__ OUT) {
    AGG_BODY()
    if (g == 0) {
        *(float4*)&OUT[i * F + fl] = o0;       // both layers have ReLU after
        *(float4*)&OUT[i * F + fl + 4] = o1;
    }
}

// layer-2 variant: pool fused via LDS run-reduce over the block's 4 nodes,
// then ~1 atomicMax per feature per block (R19 showed per-wave atomics
// serialize ~780-deep per address: 435us. Pre-reduction is essential.)
__global__ __launch_bounds__(256) void agg_pool(
    const __half* __restrict__ Hh, const float* __restrict__ S, const float* __restrict__ Dv,
    const int* __restrict__ row_ptr, const int* __restrict__ csr_src,
    const float* __restrict__ bias,
    const int* __restrict__ batch, float* __restrict__ gmax) {
    __shared__ float pout[4][F];
    __shared__ int   pbat[4];
    AGG_BODY()
    int wid = threadIdx.x >> 6;
    if (g == 0) {
        *(float4*)&pout[wid][fl] = o0;
        *(float4*)&pout[wid][fl + 4] = o1;
        if (lane == 0) pbat[wid] = batch[i];
    }
    __syncthreads();
    if (threadIdx.x < F) {
        int f = threadIdx.x;
        int curb = pbat[0];
        float mx = pout[0][f];
        #pragma unroll
        for (int r = 1; r < 4; r++) {
            int b = pbat[r];
            float v = pout[r][f];
            if (b != curb) {
                atomicMax((int*)&gmax[curb * F + f], __float_as_int(mx));
                curb = b; mx = v;
            } else {
                mx = fmaxf(mx, v);
            }
        }
        atomicMax((int*)&gmax[curb * F + f], __float_as_int(mx));
    }
}

// ---------------- final linear ----------------

__global__ void final_kernel(const float* __restrict__ gmax, const float* __restrict__ Wl,
                             const float* __restrict__ bl, float* __restrict__ out) {
    int g = blockIdx.x;
    int c = threadIdx.x;
    if (c < C_CLS) {
        float acc = bl[c];
        #pragma unroll
        for (int f = 0; f < F; f++) acc = fmaf(gmax[g * F + f], Wl[f * C_CLS + c], acc);
        out[g * C_CLS + c] = acc;
    }
}

// ---------------- launch ----------------

extern "C" void kernel_launch(void* const* d_in, const int* in_sizes, int n_in,
                              void* d_out, int out_size, void* d_ws, size_t ws_size,
                              hipStream_t stream) {
    const float* x    = (const float*)d_in[0];
    const int*   ei   = (const int*)d_in[1];
    const int*   batch= (const int*)d_in[2];
    const float* W1   = (const float*)d_in[3];
    const float* a1s  = (const float*)d_in[4];
    const float* a1d  = (const float*)d_in[5];
    const float* b1   = (const float*)d_in[6];
    const float* W2   = (const float*)d_in[7];
    const float* a2s  = (const float*)d_in[8];
    const float* a2d  = (const float*)d_in[9];
    const float* b2   = (const float*)d_in[10];
    const float* Wl   = (const float*)d_in[11];
    const float* bl   = (const float*)d_in[12];
    float* out = (float*)d_out;

    const int* src = ei;
    const int* dst = ei + N_EDGES;

    // workspace layout (256B aligned); ws is large enough for all buffers separate
    char* ws = (char*)d_ws;
    size_t off = 0;
    auto alloc = [&](size_t bytes) { size_t o = off; off += (bytes + 255) & ~(size_t)255; return o; };
    int*   row_ptr = (int*)(ws + alloc((size_t)(N_NODES + 1) * 4));
    int*   csr_src = (int*)(ws + alloc((size_t)N_EDGES * 4));
    unsigned int* bedges = (unsigned int*)(ws + alloc((size_t)N_EDGES * 4));
    __half* Hh     = (__half*)(ws + alloc((size_t)N_NODES * F * 2));
    float* hB      = (float*)(ws + alloc((size_t)N_NODES * F * 4));
    int*   Cmat    = (int*)(ws + alloc((size_t)NBUCKET * NCHUNKS * 4));
    int*   Coff    = (int*)(ws + alloc((size_t)NCHUNKS * NBUCKET * 4));
    float* Sv      = (float*)(ws + alloc((size_t)N_NODES * 4));
    float* Dv      = (float*)(ws + alloc((size_t)N_NODES * 4));
    float* gmax    = (float*)(ws + alloc((size_t)G_GRAPHS * F * 4));
    int*   gcount  = (int*)(ws + alloc((size_t)NBUCKET * 4));

    // ---- dispatch 1: chunk histograms ++ gemm1 (independent work, unioned) ----
    count_gemm1<<<NCHUNKS + GTILES, 256, 0, stream>>>(dst, Cmat, x, W1, a1s, a1d, Hh, Sv, Dv);
    // ---- CSR build (deterministic bucketed counting sort, u32 records) ----
    scan_chunk_offsets<<<NBUCKET, 512, 0, stream>>>(Cmat, Coff, gcount);
    bucket_scatter<<<NCHUNKS, 512, 0, stream>>>(src, dst, Cmat, Coff, gcount, bedges);
    bucket_csr<<<NBUCKET, 512, 0, stream>>>(bedges, gcount, row_ptr, csr_src);

    // ---- layer 1 agg: Hh/Sv/Dv ready since dispatch 1 ----
    agg_main<<<(N_NODES * 64 + 255) / 256, 256, 0, stream>>>(Hh, Sv, Dv, row_ptr, csr_src, b1, hB);

    // ---- layer 2: gemm(hB) -> Hh(fp16) -> agg (pool fused into gmax) ----
    gemm_sd_kernel<<<GTILES, 256, 0, stream>>>(hB, W2, a2s, a2d, Hh, Sv, Dv, gmax);
    agg_pool<<<(N_NODES * 64 + 255) / 256, 256, 0, stream>>>(Hh, Sv, Dv, row_ptr, csr_src, b2,
                                                             batch, gmax);

    // ---- classifier ----
    final_kernel<<<G_GRAPHS, 64, 0, stream>>>(gmax, Wl, bl, out);
}